// Round 5
// baseline (464.114 us; speedup 1.0000x reference)
//
#include <hip/hip_runtime.h>
#include <hip/hip_bf16.h>
#include <stdint.h>

// B=4, C=64, N=16384, K=16, CO=64 (fp32 I/O, int32 idx)
// R5 = R3 bodies fused into ONE kernel with a SOFTWARE grid barrier
// (regular launches only -- no cooperative API, graph-capture safe):
//  init:   zero statsN (32x128) + 2 barrier counters   (16 blocks, ~1us)
//  fused:  phase1 (= R3 k1): MFMA GEMM, block g -> tile g          (1024 tiles)
//          -- grid_barrier --
//          phase2 (= R3 k2): gather, block g -> chunks g, g+1024   (2048 chunks)
//                            ((g+1024)&7 == g&7 -> same XCD pinning)
//          -- grid_barrier --
//          phase3 (= R3 k3): stats reduce + affine + leaky + transpose
// Co-residency proof: grid 1024 = 4 blocks/CU x 256 CU exactly; LDS union
// 27.6KB <= 160/4 KB; launch_bounds(256,4) caps VGPR at 128 -> all blocks
// resident -> spin barrier cannot deadlock. Cross-XCD visibility via
// __threadfence() (device-scope release/acquire) + agent-scope atomics.
#define NDIM 16384
#define KNB 16
#define BNK_F 1048576.0f
#define GRID_N 1024u

typedef __attribute__((ext_vector_type(8))) short bf16x8_t;
typedef __attribute__((ext_vector_type(4))) float f32x4_t;

__device__ inline unsigned pack_bf16(float a, float b) {
    return (unsigned)__bfloat16_as_ushort(__float2bfloat16(a))
         | ((unsigned)__bfloat16_as_ushort(__float2bfloat16(b)) << 16);
}

__device__ inline void grid_barrier(unsigned* bar, unsigned target) {
    __syncthreads();
    if (threadIdx.x == 0) {
        __threadfence();   // release: drain stores, write back XCD L2
        __hip_atomic_fetch_add(bar, 1u, __ATOMIC_ACQ_REL, __HIP_MEMORY_SCOPE_AGENT);
        while (__hip_atomic_load(bar, __ATOMIC_ACQUIRE, __HIP_MEMORY_SCOPE_AGENT) < target) {
            __builtin_amdgcn_s_sleep(1);
        }
        __threadfence();   // acquire: invalidate stale cached lines
    }
    __syncthreads();
}

// ---------------- init: zero statsN + barrier counters ----------------
__global__ __launch_bounds__(256) void init_kernel(
    float* __restrict__ statsN, unsigned* __restrict__ bar)
{
    const int i = blockIdx.x * 256 + threadIdx.x;
    if (i < 4096) statsN[i] = 0.0f;
    if (i < 2) bar[i] = 0u;
}

// ---------------- fused: gemm | barrier | gather | barrier | out ----------------
__global__ __launch_bounds__(256, 4) void fused_kernel(
    const float* __restrict__ x,            // (B, 64, N)
    const float* __restrict__ W,            // (64, 128)
    const int* __restrict__ ei,             // (B, N, 16)
    const float* __restrict__ gamma,
    const float* __restrict__ beta,
    unsigned* __restrict__ y1p,             // (B,N,32) bf16-pairs
    unsigned* __restrict__ y2p,             // (B,N,32) bf16-pairs
    unsigned* __restrict__ hselp,           // (B,N,32) bf16-pairs
    float* __restrict__ statsN,             // (32,128) striped stats
    unsigned* __restrict__ bar,             // 2 barrier counters (zeroed by init)
    float* __restrict__ out)                // (B, 64, N)
{
    __shared__ alignas(16) union SM {
        struct { short a[128 * 72]; short b[64 * 72]; } k1;            // 27648 B
        struct { float rs[8][64]; float rq[8][64]; } k2;               //  4096 B
        struct { float tile[64 * 65]; float colsum[128];
                 float sc[64], bi[64]; } k3;                           // 17664 B
    } sm;

    const int tid = threadIdx.x;
    const int g   = blockIdx.x;

    // ================= phase 1: MFMA GEMM (R3-proven body) =================
    {
        const int b  = g >> 8;
        const int n0 = (g & 255) << 6;

        for (int idx = tid; idx < 1024; idx += 256) {
            const int r = idx >> 4, q = idx & 15;
            const f32x4_t wa = *(const f32x4_t*)&W[r * 128 + q * 4];
            const f32x4_t wb = *(const f32x4_t*)&W[r * 128 + 64 + q * 4];
            uint2 pa = { pack_bf16(wa[0] + wb[0], wa[1] + wb[1]),
                         pack_bf16(wa[2] + wb[2], wa[3] + wb[3]) };
            uint2 pb = { pack_bf16(wb[0], wb[1]), pack_bf16(wb[2], wb[3]) };
            *(uint2*)&sm.k1.a[r * 72 + q * 4]        = pa;
            *(uint2*)&sm.k1.a[(64 + r) * 72 + q * 4] = pb;
        }
        {
            const float* xb = x + (size_t)b * 64 * NDIM + n0;
            const int n = tid & 63;
            unsigned* lb32 = (unsigned*)sm.k1.b;
            for (int cp = tid >> 6; cp < 32; cp += 4) {
                int c = cp * 2;
                float x0 = xb[(size_t)c * NDIM + n];
                float x1 = xb[(size_t)(c + 1) * NDIM + n];
                lb32[n * 36 + cp] = pack_bf16(x0, x1);
            }
        }
        __syncthreads();

        const int lane = tid & 63;
        const int w    = tid >> 6;
        const int m    = lane & 15;
        const int q    = lane >> 4;
        const int n    = w * 16 + m;

        const bf16x8_t b0 = *(const bf16x8_t*)&sm.k1.b[n * 72 + q * 8];
        const bf16x8_t b1 = *(const bf16x8_t*)&sm.k1.b[n * 72 + q * 8 + 32];

        const size_t rowbase = ((size_t)(b * NDIM + n0 + n)) * 32;
        #pragma unroll
        for (int t = 0; t < 8; ++t) {
            const short* ap = &sm.k1.a[(t * 16 + m) * 72 + q * 8];
            bf16x8_t a0 = *(const bf16x8_t*)ap;
            bf16x8_t a1 = *(const bf16x8_t*)(ap + 32);
            f32x4_t acc = {0.f, 0.f, 0.f, 0.f};
            acc = __builtin_amdgcn_mfma_f32_16x16x32_bf16(a0, b0, acc, 0, 0, 0);
            acc = __builtin_amdgcn_mfma_f32_16x16x32_bf16(a1, b1, acc, 0, 0, 0);
            unsigned* dst = (t < 4) ? y1p : y2p;
            uint2 pk = { pack_bf16(acc[0], acc[1]), pack_bf16(acc[2], acc[3]) };
            *(uint2*)&dst[rowbase + (t & 3) * 8 + q * 2] = pk;
        }
    }

    grid_barrier(&bar[0], GRID_N);

    // ================= phase 2: gather (R3-proven body, 2 chunks) =================
    {
        const int w    = __builtin_amdgcn_readfirstlane(tid >> 6);
        const int lane = tid & 63;
        const int half = lane >> 5;
        const int c2   = lane & 31;

        const unsigned sgn0 = (gamma[2 * c2]     >= 0.0f) ? 0x80000000u : 0u;
        const unsigned sgn1 = (gamma[2 * c2 + 1] >= 0.0f) ? 0x80000000u : 0u;
        const unsigned coff = (unsigned)(c2 << 2);

        #pragma unroll 1
        for (int t2 = 0; t2 < 2; ++t2) {
            const int g2   = g + t2 * 1024;
            const int xcd  = g2 & 7;
            const int b    = xcd >> 1;
            const int row0 = b * NDIM + (xcd & 1) * 8192 + (g2 >> 3) * 32 + w * 8;
            const char* y2base = (const char*)y2p + (size_t)b * NDIM * 128;

            float ssum0 = 0.f, ssum1 = 0.f, ssq0 = 0.f, ssq1 = 0.f;

            for (int rp = 0; rp < 8; rp += 4) {
                const int ra = row0 + rp;
                const int rb = ra + 2;
                const int* iA = ei + (size_t)ra * KNB;
                const int* iB = ei + (size_t)(ra + 1) * KNB;
                const int* iC = ei + (size_t)rb * KNB;
                const int* iD = ei + (size_t)(rb + 1) * KNB;

                unsigned u0[KNB], u1[KNB];
                #pragma unroll
                for (int k = 0; k < KNB; ++k) {
                    int j = half ? iB[k] : iA[k];
                    u0[k] = *(const unsigned*)(y2base + ((((unsigned)j) << 7) + coff));
                }
                #pragma unroll
                for (int k = 0; k < KNB; ++k) {
                    int j = half ? iD[k] : iC[k];
                    u1[k] = *(const unsigned*)(y2base + ((((unsigned)j) << 7) + coff));
                }
                const unsigned y1u0 = y1p[(size_t)(ra + half) * 32 + c2];
                const unsigned y1u1 = y1p[(size_t)(rb + half) * 32 + c2];

                #pragma unroll 2
                for (int p = 0; p < 2; ++p) {
                    const unsigned* u = (p == 0) ? u0 : u1;
                    const unsigned y1u = (p == 0) ? y1u0 : y1u1;
                    const int rw = ((p == 0) ? ra : rb) + half;

                    float s20 = 0.f, s21 = 0.f, q20 = 0.f, q21 = 0.f;
                    float M0 = -3.402823e38f, M1 = -3.402823e38f;
                    #pragma unroll
                    for (int k = 0; k < KNB; k += 2) {
                        unsigned lo0 = u[k] << 16,     hi0 = u[k] & 0xffff0000u;
                        unsigned lo1 = u[k + 1] << 16, hi1 = u[k + 1] & 0xffff0000u;
                        float v00 = __uint_as_float(lo0), v01 = __uint_as_float(hi0);
                        float v10 = __uint_as_float(lo1), v11 = __uint_as_float(hi1);
                        s20 += v00;                s21 += v01;
                        q20 = fmaf(v00, v00, q20); q21 = fmaf(v01, v01, q21);
                        s20 += v10;                s21 += v11;
                        q20 = fmaf(v10, v10, q20); q21 = fmaf(v11, v11, q21);
                        M0 = fmaxf(fmaxf(M0, __uint_as_float(lo0 ^ sgn0)),
                                   __uint_as_float(lo1 ^ sgn0));
                        M1 = fmaxf(fmaxf(M1, __uint_as_float(hi0 ^ sgn1)),
                                   __uint_as_float(hi1 ^ sgn1));
                    }
                    const float y1lo = __uint_as_float(y1u << 16);
                    const float y1hi = __uint_as_float(y1u & 0xffff0000u);
                    const float h0 = y1lo - __uint_as_float(__float_as_uint(M0) ^ sgn0);
                    const float h1 = y1hi - __uint_as_float(__float_as_uint(M1) ^ sgn1);
                    hselp[(size_t)rw * 32 + c2] = pack_bf16(h0, h1);
                    ssum0 += 16.f * y1lo - s20;
                    ssum1 += 16.f * y1hi - s21;
                    ssq0  += fmaf(fmaf(-2.f, s20, 16.f * y1lo), y1lo, q20);
                    ssq1  += fmaf(fmaf(-2.f, s21, 16.f * y1hi), y1hi, q21);
                }
            }

            if (t2 == 1) __syncthreads();   // protect rs/rq reuse (2nd chunk)
            sm.k2.rs[w * 2 + half][c2 * 2]     = ssum0;
            sm.k2.rs[w * 2 + half][c2 * 2 + 1] = ssum1;
            sm.k2.rq[w * 2 + half][c2 * 2]     = ssq0;
            sm.k2.rq[w * 2 + half][c2 * 2 + 1] = ssq1;
            __syncthreads();
            if (tid < 128) {
                const int c = tid & 63;
                float v = 0.f;
                if (tid < 64) { for (int r = 0; r < 8; ++r) v += sm.k2.rs[r][c]; }
                else          { for (int r = 0; r < 8; ++r) v += sm.k2.rq[r][c]; }
                atomicAdd(&statsN[(g2 & 31) * 128 + tid], v);
            }
        }
    }

    grid_barrier(&bar[1], GRID_N);

    // ================= phase 3: reduce + affine + leaky + transpose =================
    {
        if (tid < 128) {
            float v = 0.f;
            #pragma unroll
            for (int i = 0; i < 32; ++i) v += statsN[i * 128 + tid];
            sm.k3.colsum[tid] = v;
        }
        __syncthreads();
        if (tid < 64) {
            float mean = sm.k3.colsum[tid] * (1.0f / BNK_F);
            float var  = sm.k3.colsum[64 + tid] * (1.0f / BNK_F) - mean * mean;
            float s    = gamma[tid] * rsqrtf(var + 1e-5f);
            sm.k3.sc[tid] = s;
            sm.k3.bi[tid] = beta[tid] - mean * s;
        }
        __syncthreads();

        const int b  = g >> 8;
        const int n0 = (g & 255) << 6;
        const size_t bn0 = (size_t)b * NDIM + n0;
        const int c4 = tid & 15;

        for (int r = tid >> 4; r < 64; r += 16) {
            uint2 u = *(const uint2*)&hselp[(bn0 + r) * 32 + c4 * 2];
            float v0 = fmaf(sm.k3.sc[4 * c4],     __uint_as_float(u.x << 16),         sm.k3.bi[4 * c4]);
            float v1 = fmaf(sm.k3.sc[4 * c4 + 1], __uint_as_float(u.x & 0xffff0000u), sm.k3.bi[4 * c4 + 1]);
            float v2 = fmaf(sm.k3.sc[4 * c4 + 2], __uint_as_float(u.y << 16),         sm.k3.bi[4 * c4 + 2]);
            float v3 = fmaf(sm.k3.sc[4 * c4 + 3], __uint_as_float(u.y & 0xffff0000u), sm.k3.bi[4 * c4 + 3]);
            v0 = (v0 >= 0.f) ? v0 : 0.2f * v0;
            v1 = (v1 >= 0.f) ? v1 : 0.2f * v1;
            v2 = (v2 >= 0.f) ? v2 : 0.2f * v2;
            v3 = (v3 >= 0.f) ? v3 : 0.2f * v3;
            sm.k3.tile[r * 65 + 4 * c4]     = v0;
            sm.k3.tile[r * 65 + 4 * c4 + 1] = v1;
            sm.k3.tile[r * 65 + 4 * c4 + 2] = v2;
            sm.k3.tile[r * 65 + 4 * c4 + 3] = v3;
        }
        __syncthreads();
        const int ln = tid & 15;
        for (int o = tid >> 4; o < 64; o += 16) {
            f32x4_t v;
            v[0] = sm.k3.tile[(ln * 4 + 0) * 65 + o];
            v[1] = sm.k3.tile[(ln * 4 + 1) * 65 + o];
            v[2] = sm.k3.tile[(ln * 4 + 2) * 65 + o];
            v[3] = sm.k3.tile[(ln * 4 + 3) * 65 + o];
            *(f32x4_t*)&out[((size_t)(b * 64 + o) << 14) + n0 + ln * 4] = v;
        }
    }
}

extern "C" void kernel_launch(void* const* d_in, const int* in_sizes, int n_in,
                              void* d_out, int out_size, void* d_ws, size_t ws_size,
                              hipStream_t stream) {
    const float* x     = (const float*)d_in[0];
    const int*   ei    = (const int*)d_in[1];
    const float* W     = (const float*)d_in[2];
    const float* gamma = (const float*)d_in[3];
    const float* beta  = (const float*)d_in[4];
    float* out = (float*)d_out;

    char* ws = (char*)d_ws;
    unsigned* y1p    = (unsigned*)(ws);                       // 8 MiB (bf16 pairs)
    unsigned* y2p    = (unsigned*)(ws + 8388608);             // 8 MiB
    unsigned* hselp  = (unsigned*)(ws + 16777216);            // 8 MiB
    float*    statsN = (float*)(ws + 25165824);               // 16 KiB (32x128)
    unsigned* bar    = (unsigned*)(ws + 25182208);            // 2 counters

    init_kernel  <<<dim3(16),   dim3(256), 0, stream>>>(statsN, bar);
    fused_kernel <<<dim3(1024), dim3(256), 0, stream>>>(x, W, ei, gamma, beta,
                                                        y1p, y2p, hselp, statsN,
                                                        bar, out);
}

// Round 6
// 220.860 us; speedup vs baseline: 2.1014x; 2.1014x over previous
//
#include <hip/hip_runtime.h>
#include <hip/hip_bf16.h>
#include <stdint.h>

// B=4, C=64, N=16384, K=16, CO=64 (fp32 I/O, int32 idx)
// R6 = PROFILING PROBE. R3-proven bodies, each kernel repeats its body
// in-kernel (k1 x8, k2 x4, k3 x16) so every dispatch exceeds the 45us
// fill threshold and appears in the top-5 counter table with its own
// dur/VGPR/occupancy/VALUBusy. Numerically identical output (k2's
// atomicAdd fires only on the last rep; k1/k3 are pure/idempotent).
// Per-kernel true dur = dispatch dur / REP. Will be reverted to REP=1
// next round with the targeted fix.
#define NDIM 16384
#define KNB 16
#define BNK_F 1048576.0f
#define REP1 8
#define REP2 4
#define REP3 16

typedef __attribute__((ext_vector_type(8))) short bf16x8_t;
typedef __attribute__((ext_vector_type(4))) float f32x4_t;

__device__ inline unsigned pack_bf16(float a, float b) {
    return (unsigned)__bfloat16_as_ushort(__float2bfloat16(a))
         | ((unsigned)__bfloat16_as_ushort(__float2bfloat16(b)) << 16);
}

// ---------------- Kernel 1: MFMA GEMM (R3 body, x REP1) ----------------
__global__ __launch_bounds__(256) void gemm_mfma_kernel(
    const float* __restrict__ x,            // (B, 64, N)
    const float* __restrict__ W,            // (64, 128)
    unsigned* __restrict__ y1p,             // (B,N,32) bf16-pairs
    unsigned* __restrict__ y2p,             // (B,N,32) bf16-pairs
    float* __restrict__ statsN)             // (32,128) striped stats - zeroed here
{
    __shared__ alignas(16) short lds_a[128 * 72];  // row pad 72 -> 2-way-free b128
    __shared__ alignas(16) short lds_b[64 * 72];   // x tile, n-major

    const int tid = threadIdx.x;
    const int b  = blockIdx.x >> 8;
    const int n0 = (blockIdx.x & 255) << 6;

    for (int rep = 0; rep < REP1; ++rep) {
        asm volatile("" ::: "memory");
        if (blockIdx.x == 0) {
            for (int i = tid; i < 4096; i += 256) statsN[i] = 0.0f;
        }
        // stage A (bf16) via float4: 1024 (row r, float4-col q) pairs.
        for (int idx = tid; idx < 1024; idx += 256) {
            const int r = idx >> 4, q = idx & 15;
            const f32x4_t wa = *(const f32x4_t*)&W[r * 128 + q * 4];
            const f32x4_t wb = *(const f32x4_t*)&W[r * 128 + 64 + q * 4];
            uint2 pa = { pack_bf16(wa[0] + wb[0], wa[1] + wb[1]),
                         pack_bf16(wa[2] + wb[2], wa[3] + wb[3]) };
            uint2 pb = { pack_bf16(wb[0], wb[1]), pack_bf16(wb[2], wb[3]) };
            *(uint2*)&lds_a[r * 72 + q * 4]        = pa;
            *(uint2*)&lds_a[(64 + r) * 72 + q * 4] = pb;
        }
        // stage B: x (c-major fp32) -> lds_b[n][c] bf16, packed-pair writes
        {
            const float* xb = x + (size_t)b * 64 * NDIM + n0;
            const int n = tid & 63;
            unsigned* lb32 = (unsigned*)lds_b;
            for (int cp = tid >> 6; cp < 32; cp += 4) {
                int c = cp * 2;
                float x0 = xb[(size_t)c * NDIM + n];
                float x1 = xb[(size_t)(c + 1) * NDIM + n];
                lb32[n * 36 + cp] = pack_bf16(x0, x1);
            }
        }
        __syncthreads();

        const int lane = tid & 63;
        const int w    = tid >> 6;
        const int m    = lane & 15;
        const int q    = lane >> 4;
        const int n    = w * 16 + m;

        const bf16x8_t b0 = *(const bf16x8_t*)&lds_b[n * 72 + q * 8];
        const bf16x8_t b1 = *(const bf16x8_t*)&lds_b[n * 72 + q * 8 + 32];

        const size_t rowbase = ((size_t)(b * NDIM + n0 + n)) * 32;
        #pragma unroll
        for (int t = 0; t < 8; ++t) {
            const short* ap = &lds_a[(t * 16 + m) * 72 + q * 8];
            bf16x8_t a0 = *(const bf16x8_t*)ap;
            bf16x8_t a1 = *(const bf16x8_t*)(ap + 32);
            f32x4_t acc = {0.f, 0.f, 0.f, 0.f};
            acc = __builtin_amdgcn_mfma_f32_16x16x32_bf16(a0, b0, acc, 0, 0, 0);
            acc = __builtin_amdgcn_mfma_f32_16x16x32_bf16(a1, b1, acc, 0, 0, 0);
            unsigned* dst = (t < 4) ? y1p : y2p;
            uint2 pk = { pack_bf16(acc[0], acc[1]), pack_bf16(acc[2], acc[3]) };
            *(uint2*)&dst[rowbase + (t & 3) * 8 + q * 2] = pk;
        }
        __syncthreads();   // LDS reuse across reps
    }
}

// ---------------- Kernel 2: gather (R3 body, x REP2, add-on-last-rep) ----------------
__global__ __launch_bounds__(256, 4) void gather_kernel(
    const unsigned* __restrict__ y1p,        // (B,N,32) bf16-pairs
    const unsigned* __restrict__ y2p,
    const int* __restrict__ ei,              // (B, N, 16)
    const float* __restrict__ gamma,
    unsigned* __restrict__ hselp,            // (B,N,32) bf16-pairs
    float* __restrict__ statsN)              // (32,128)
{
    const int tid  = threadIdx.x;
    const int w    = __builtin_amdgcn_readfirstlane(tid >> 6);
    const int lane = tid & 63;
    const int half = lane >> 5;
    const int c2   = lane & 31;
    const int g    = blockIdx.x;
    const int xcd  = g & 7;
    const int b    = xcd >> 1;
    const int row0 = b * NDIM + (xcd & 1) * 8192 + (g >> 3) * 32 + w * 8;

    const unsigned sgn0 = (gamma[2 * c2]     >= 0.0f) ? 0x80000000u : 0u;
    const unsigned sgn1 = (gamma[2 * c2 + 1] >= 0.0f) ? 0x80000000u : 0u;
    const char* y2base = (const char*)y2p + (size_t)b * NDIM * 128;
    const unsigned coff = (unsigned)(c2 << 2);

    __shared__ float rs[8][64];
    __shared__ float rq[8][64];

    for (int rep = 0; rep < REP2; ++rep) {
        asm volatile("" ::: "memory");
        float ssum0 = 0.f, ssum1 = 0.f, ssq0 = 0.f, ssq1 = 0.f;

        for (int rp = 0; rp < 8; rp += 4) {
            const int ra = row0 + rp;
            const int rb = ra + 2;
            const int* iA = ei + (size_t)ra * KNB;
            const int* iB = ei + (size_t)(ra + 1) * KNB;
            const int* iC = ei + (size_t)rb * KNB;
            const int* iD = ei + (size_t)(rb + 1) * KNB;

            unsigned u0[KNB], u1[KNB];
            #pragma unroll
            for (int k = 0; k < KNB; ++k) {
                int j = half ? iB[k] : iA[k];
                u0[k] = *(const unsigned*)(y2base + ((((unsigned)j) << 7) + coff));
            }
            #pragma unroll
            for (int k = 0; k < KNB; ++k) {
                int j = half ? iD[k] : iC[k];
                u1[k] = *(const unsigned*)(y2base + ((((unsigned)j) << 7) + coff));
            }
            const unsigned y1u0 = y1p[(size_t)(ra + half) * 32 + c2];
            const unsigned y1u1 = y1p[(size_t)(rb + half) * 32 + c2];

            #pragma unroll 2
            for (int p = 0; p < 2; ++p) {
                const unsigned* u = (p == 0) ? u0 : u1;
                const unsigned y1u = (p == 0) ? y1u0 : y1u1;
                const int rw = ((p == 0) ? ra : rb) + half;

                float s20 = 0.f, s21 = 0.f, q20 = 0.f, q21 = 0.f;
                float M0 = -3.402823e38f, M1 = -3.402823e38f;
                #pragma unroll
                for (int k = 0; k < KNB; k += 2) {
                    unsigned lo0 = u[k] << 16,     hi0 = u[k] & 0xffff0000u;
                    unsigned lo1 = u[k + 1] << 16, hi1 = u[k + 1] & 0xffff0000u;
                    float v00 = __uint_as_float(lo0), v01 = __uint_as_float(hi0);
                    float v10 = __uint_as_float(lo1), v11 = __uint_as_float(hi1);
                    s20 += v00;                s21 += v01;
                    q20 = fmaf(v00, v00, q20); q21 = fmaf(v01, v01, q21);
                    s20 += v10;                s21 += v11;
                    q20 = fmaf(v10, v10, q20); q21 = fmaf(v11, v11, q21);
                    M0 = fmaxf(fmaxf(M0, __uint_as_float(lo0 ^ sgn0)),
                               __uint_as_float(lo1 ^ sgn0));
                    M1 = fmaxf(fmaxf(M1, __uint_as_float(hi0 ^ sgn1)),
                               __uint_as_float(hi1 ^ sgn1));
                }
                const float y1lo = __uint_as_float(y1u << 16);
                const float y1hi = __uint_as_float(y1u & 0xffff0000u);
                const float h0 = y1lo - __uint_as_float(__float_as_uint(M0) ^ sgn0);
                const float h1 = y1hi - __uint_as_float(__float_as_uint(M1) ^ sgn1);
                hselp[(size_t)rw * 32 + c2] = pack_bf16(h0, h1);
                ssum0 += 16.f * y1lo - s20;
                ssum1 += 16.f * y1hi - s21;
                ssq0  += fmaf(fmaf(-2.f, s20, 16.f * y1lo), y1lo, q20);
                ssq1  += fmaf(fmaf(-2.f, s21, 16.f * y1hi), y1hi, q21);
            }
        }

        rs[w * 2 + half][c2 * 2]     = ssum0;
        rs[w * 2 + half][c2 * 2 + 1] = ssum1;
        rq[w * 2 + half][c2 * 2]     = ssq0;
        rq[w * 2 + half][c2 * 2 + 1] = ssq1;
        __syncthreads();
        if (rep == REP2 - 1 && tid < 128) {     // stats add only once
            const int c = tid & 63;
            float v = 0.f;
            if (tid < 64) { for (int r = 0; r < 8; ++r) v += rs[r][c]; }
            else          { for (int r = 0; r < 8; ++r) v += rq[r][c]; }
            atomicAdd(&statsN[(g & 31) * 128 + tid], v);
        }
        __syncthreads();   // rs/rq reuse across reps
    }
}

// ---------------- Kernel 3: out (R3 body, x REP3) ----------------
__global__ __launch_bounds__(256) void out_kernel(
    const unsigned* __restrict__ hselp,      // (B,N,32) bf16-pairs
    const float* __restrict__ statsN,        // (32,128)
    const float* __restrict__ gamma,
    const float* __restrict__ beta,
    float* __restrict__ out)                 // (B, 64, N)
{
    __shared__ float tile[64 * 65];
    __shared__ float colsum[128];
    __shared__ float sc[64], bi[64];
    const int tid = threadIdx.x;
    const int b  = blockIdx.x >> 8;
    const int n0 = (blockIdx.x & 255) << 6;
    const size_t bn0 = (size_t)b * NDIM + n0;
    const int c4 = tid & 15;

    for (int rep = 0; rep < REP3; ++rep) {
        asm volatile("" ::: "memory");
        if (tid < 128) {
            float v = 0.f;
            #pragma unroll
            for (int i = 0; i < 32; ++i) v += statsN[i * 128 + tid];
            colsum[tid] = v;
        }
        __syncthreads();
        if (tid < 64) {
            float mean = colsum[tid] * (1.0f / BNK_F);
            float var  = colsum[64 + tid] * (1.0f / BNK_F) - mean * mean;
            float s    = gamma[tid] * rsqrtf(var + 1e-5f);
            sc[tid] = s;
            bi[tid] = beta[tid] - mean * s;
        }
        __syncthreads();

        for (int r = tid >> 4; r < 64; r += 16) {
            uint2 u = *(const uint2*)&hselp[(bn0 + r) * 32 + c4 * 2];
            float v0 = fmaf(sc[4 * c4],     __uint_as_float(u.x << 16),         bi[4 * c4]);
            float v1 = fmaf(sc[4 * c4 + 1], __uint_as_float(u.x & 0xffff0000u), bi[4 * c4 + 1]);
            float v2 = fmaf(sc[4 * c4 + 2], __uint_as_float(u.y << 16),         bi[4 * c4 + 2]);
            float v3 = fmaf(sc[4 * c4 + 3], __uint_as_float(u.y & 0xffff0000u), bi[4 * c4 + 3]);
            v0 = (v0 >= 0.f) ? v0 : 0.2f * v0;
            v1 = (v1 >= 0.f) ? v1 : 0.2f * v1;
            v2 = (v2 >= 0.f) ? v2 : 0.2f * v2;
            v3 = (v3 >= 0.f) ? v3 : 0.2f * v3;
            tile[r * 65 + 4 * c4]     = v0;
            tile[r * 65 + 4 * c4 + 1] = v1;
            tile[r * 65 + 4 * c4 + 2] = v2;
            tile[r * 65 + 4 * c4 + 3] = v3;
        }
        __syncthreads();
        const int ln = tid & 15;
        for (int o = tid >> 4; o < 64; o += 16) {
            f32x4_t v;
            v[0] = tile[(ln * 4 + 0) * 65 + o];
            v[1] = tile[(ln * 4 + 1) * 65 + o];
            v[2] = tile[(ln * 4 + 2) * 65 + o];
            v[3] = tile[(ln * 4 + 3) * 65 + o];
            *(f32x4_t*)&out[((size_t)(b * 64 + o) << 14) + n0 + ln * 4] = v;
        }
        __syncthreads();   // tile reuse across reps
    }
}

extern "C" void kernel_launch(void* const* d_in, const int* in_sizes, int n_in,
                              void* d_out, int out_size, void* d_ws, size_t ws_size,
                              hipStream_t stream) {
    const float* x     = (const float*)d_in[0];
    const int*   ei    = (const int*)d_in[1];
    const float* W     = (const float*)d_in[2];
    const float* gamma = (const float*)d_in[3];
    const float* beta  = (const float*)d_in[4];
    float* out = (float*)d_out;

    char* ws = (char*)d_ws;
    unsigned* y1p    = (unsigned*)(ws);                       // 8 MiB (bf16 pairs)
    unsigned* y2p    = (unsigned*)(ws + 8388608);             // 8 MiB
    unsigned* hselp  = (unsigned*)(ws + 16777216);            // 8 MiB
    float*    statsN = (float*)(ws + 25165824);               // 16 KiB (32x128)

    gemm_mfma_kernel <<<dim3(1024), dim3(256), 0, stream>>>(x, W, y1p, y2p, statsN);
    gather_kernel    <<<dim3(2048), dim3(256), 0, stream>>>(y1p, y2p, ei, gamma, hselp, statsN);
    out_kernel       <<<dim3(1024), dim3(256), 0, stream>>>(hselp, statsN, gamma, beta, out);
}

// Round 7
// 104.216 us; speedup vs baseline: 4.4534x; 2.1192x over previous
//
#include <hip/hip_runtime.h>
#include <hip/hip_bf16.h>
#include <stdint.h>

// B=4, C=64, N=16384, K=16, CO=64 (fp32 I/O, int32 idx)
// R7 = R3 structure + packed-FP32 (v_pk_add/fma_f32) accumulation in k2.
// R6 probe attribution: k1<=7.7us, k2~15.5us (VALUBusy 54%, HBM 10%),
// k3<=3.9us (at HBM floor); ~75us of bench dur is harness fixed cost.
// k2 is the only target: cut VALU stream via f32x2 accumulators -> pk ops.
#define NDIM 16384
#define KNB 16
#define BNK_F 1048576.0f

typedef __attribute__((ext_vector_type(8))) short bf16x8_t;
typedef __attribute__((ext_vector_type(4))) float f32x4_t;
typedef __attribute__((ext_vector_type(2))) float f32x2_t;

__device__ inline unsigned pack_bf16(float a, float b) {
    return (unsigned)__bfloat16_as_ushort(__float2bfloat16(a))
         | ((unsigned)__bfloat16_as_ushort(__float2bfloat16(b)) << 16);
}

// ---------------- Kernel 1: MFMA GEMM (R3-proven; vector W add) ----------------
__global__ __launch_bounds__(256) void gemm_mfma_kernel(
    const float* __restrict__ x,            // (B, 64, N)
    const float* __restrict__ W,            // (64, 128)
    unsigned* __restrict__ y1p,             // (B,N,32) bf16-pairs
    unsigned* __restrict__ y2p,             // (B,N,32) bf16-pairs
    float* __restrict__ statsN)             // (32,128) striped stats - zeroed here
{
    __shared__ alignas(16) short lds_a[128 * 72];  // row pad 72 -> 2-way-free b128
    __shared__ alignas(16) short lds_b[64 * 72];   // x tile, n-major

    const int tid = threadIdx.x;
    if (blockIdx.x == 0) {
        for (int i = tid; i < 4096; i += 256) statsN[i] = 0.0f;
    }
    const int b  = blockIdx.x >> 8;
    const int n0 = (blockIdx.x & 255) << 6;

    // stage A (bf16) via float4: 1024 (row r, float4-col q) pairs.
    for (int idx = tid; idx < 1024; idx += 256) {
        const int r = idx >> 4, q = idx & 15;
        const f32x4_t wa = *(const f32x4_t*)&W[r * 128 + q * 4];
        const f32x4_t wb = *(const f32x4_t*)&W[r * 128 + 64 + q * 4];
        const f32x4_t wsum = wa + wb;                  // 2x v_pk_add_f32
        uint2 pa = { pack_bf16(wsum[0], wsum[1]), pack_bf16(wsum[2], wsum[3]) };
        uint2 pb = { pack_bf16(wb[0], wb[1]),     pack_bf16(wb[2], wb[3]) };
        *(uint2*)&lds_a[r * 72 + q * 4]        = pa;
        *(uint2*)&lds_a[(64 + r) * 72 + q * 4] = pb;
    }
    // stage B: x (c-major fp32) -> lds_b[n][c] bf16, packed-pair writes
    {
        const float* xb = x + (size_t)b * 64 * NDIM + n0;
        const int n = tid & 63;
        unsigned* lb32 = (unsigned*)lds_b;
        for (int cp = tid >> 6; cp < 32; cp += 4) {
            int c = cp * 2;
            float x0 = xb[(size_t)c * NDIM + n];
            float x1 = xb[(size_t)(c + 1) * NDIM + n];
            lb32[n * 36 + cp] = pack_bf16(x0, x1);
        }
    }
    __syncthreads();

    const int lane = tid & 63;
    const int w    = tid >> 6;
    const int m    = lane & 15;
    const int q    = lane >> 4;
    const int n    = w * 16 + m;

    const bf16x8_t b0 = *(const bf16x8_t*)&lds_b[n * 72 + q * 8];
    const bf16x8_t b1 = *(const bf16x8_t*)&lds_b[n * 72 + q * 8 + 32];

    const size_t rowbase = ((size_t)(b * NDIM + n0 + n)) * 32;
    #pragma unroll
    for (int t = 0; t < 8; ++t) {
        const short* ap = &lds_a[(t * 16 + m) * 72 + q * 8];
        bf16x8_t a0 = *(const bf16x8_t*)ap;
        bf16x8_t a1 = *(const bf16x8_t*)(ap + 32);
        f32x4_t acc = {0.f, 0.f, 0.f, 0.f};
        acc = __builtin_amdgcn_mfma_f32_16x16x32_bf16(a0, b0, acc, 0, 0, 0);
        acc = __builtin_amdgcn_mfma_f32_16x16x32_bf16(a1, b1, acc, 0, 0, 0);
        unsigned* dst = (t < 4) ? y1p : y2p;
        uint2 pk = { pack_bf16(acc[0], acc[1]), pack_bf16(acc[2], acc[3]) };
        *(uint2*)&dst[rowbase + (t & 3) * 8 + q * 2] = pk;
    }
}

// ---------------- Kernel 2: gather, packed-f32 accumulation ----------------
// 2048 blocks x 256, XCD-pinned batches. 32 outstanding gathers/wave (R0 bursts).
__global__ __launch_bounds__(256, 4) void gather_kernel(
    const unsigned* __restrict__ y1p,        // (B,N,32) bf16-pairs
    const unsigned* __restrict__ y2p,
    const int* __restrict__ ei,              // (B, N, 16)
    const float* __restrict__ gamma,
    unsigned* __restrict__ hselp,            // (B,N,32) bf16-pairs
    float* __restrict__ statsN)              // (32,128)
{
    const int tid  = threadIdx.x;
    const int w    = __builtin_amdgcn_readfirstlane(tid >> 6);
    const int lane = tid & 63;
    const int half = lane >> 5;
    const int c2   = lane & 31;
    const int g    = blockIdx.x;
    const int xcd  = g & 7;
    const int b    = xcd >> 1;
    const int row0 = b * NDIM + (xcd & 1) * 8192 + (g >> 3) * 32 + w * 8;

    const unsigned sgn0 = (gamma[2 * c2]     >= 0.0f) ? 0x80000000u : 0u;
    const unsigned sgn1 = (gamma[2 * c2 + 1] >= 0.0f) ? 0x80000000u : 0u;
    const char* y2base = (const char*)y2p + (size_t)b * NDIM * 128;
    const unsigned coff = (unsigned)(c2 << 2);

    f32x2_t ssum = {0.f, 0.f};
    f32x2_t ssq  = {0.f, 0.f};

    for (int rp = 0; rp < 8; rp += 4) {
        const int ra = row0 + rp;            // pair0: rows ra, ra+1
        const int rb = ra + 2;               // pair1: rows rb, rb+1
        const int* iA = ei + (size_t)ra * KNB;        // wave-uniform -> s_load
        const int* iB = ei + (size_t)(ra + 1) * KNB;
        const int* iC = ei + (size_t)rb * KNB;
        const int* iD = ei + (size_t)(rb + 1) * KNB;

        unsigned u0[KNB], u1[KNB];
        #pragma unroll
        for (int k = 0; k < KNB; ++k) {
            int j = half ? iB[k] : iA[k];
            u0[k] = *(const unsigned*)(y2base + ((((unsigned)j) << 7) + coff));
        }
        #pragma unroll
        for (int k = 0; k < KNB; ++k) {
            int j = half ? iD[k] : iC[k];
            u1[k] = *(const unsigned*)(y2base + ((((unsigned)j) << 7) + coff));
        }
        const unsigned y1u0 = y1p[(size_t)(ra + half) * 32 + c2];
        const unsigned y1u1 = y1p[(size_t)(rb + half) * 32 + c2];

        #pragma unroll 2
        for (int p = 0; p < 2; ++p) {
            const unsigned* u = (p == 0) ? u0 : u1;
            const unsigned y1u = (p == 0) ? y1u0 : y1u1;
            const int rw = ((p == 0) ? ra : rb) + half;

            f32x2_t s2 = {0.f, 0.f};
            f32x2_t q2 = {0.f, 0.f};
            float M0 = -3.402823e38f, M1 = -3.402823e38f;
            #pragma unroll
            for (int k = 0; k < KNB; k += 2) {
                unsigned lo0 = u[k] << 16,     hi0 = u[k] & 0xffff0000u;
                unsigned lo1 = u[k + 1] << 16, hi1 = u[k + 1] & 0xffff0000u;
                f32x2_t v0 = { __uint_as_float(lo0), __uint_as_float(hi0) };
                f32x2_t v1 = { __uint_as_float(lo1), __uint_as_float(hi1) };
                s2 += v0;                                          // v_pk_add_f32
                q2 = __builtin_elementwise_fma(v0, v0, q2);        // v_pk_fma_f32
                s2 += v1;
                q2 = __builtin_elementwise_fma(v1, v1, q2);
                // paired -> v_max3_f32 (order-independent: bit-identical)
                M0 = fmaxf(fmaxf(M0, __uint_as_float(lo0 ^ sgn0)),
                           __uint_as_float(lo1 ^ sgn0));
                M1 = fmaxf(fmaxf(M1, __uint_as_float(hi0 ^ sgn1)),
                           __uint_as_float(hi1 ^ sgn1));
            }
            const f32x2_t y1v = { __uint_as_float(y1u << 16),
                                  __uint_as_float(y1u & 0xffff0000u) };
            const float h0 = y1v.x - __uint_as_float(__float_as_uint(M0) ^ sgn0);
            const float h1 = y1v.y - __uint_as_float(__float_as_uint(M1) ^ sgn1);
            hselp[(size_t)rw * 32 + c2] = pack_bf16(h0, h1);
            ssum += (f32x2_t){16.f, 16.f} * y1v - s2;              // pk mul/sub
            ssq  += __builtin_elementwise_fma(
                        __builtin_elementwise_fma((f32x2_t){-2.f, -2.f}, s2,
                                                  (f32x2_t){16.f, 16.f} * y1v),
                        y1v, q2);
        }
    }

    __shared__ float rs[8][64];
    __shared__ float rq[8][64];
    rs[w * 2 + half][c2 * 2]     = ssum.x;
    rs[w * 2 + half][c2 * 2 + 1] = ssum.y;
    rq[w * 2 + half][c2 * 2]     = ssq.x;
    rq[w * 2 + half][c2 * 2 + 1] = ssq.y;
    __syncthreads();
    if (tid < 128) {
        const int c = tid & 63;
        float v = 0.f;
        if (tid < 64) { for (int r = 0; r < 8; ++r) v += rs[r][c]; }
        else          { for (int r = 0; r < 8; ++r) v += rq[r][c]; }
        atomicAdd(&statsN[(g & 31) * 128 + tid], v);   // striped: ~64 adds/line
    }
}

// ---------------- Kernel 3: reduce-in-prologue + affine + leaky + transpose ----------------
__global__ __launch_bounds__(256) void out_kernel(
    const unsigned* __restrict__ hselp,      // (B,N,32) bf16-pairs
    const float* __restrict__ statsN,        // (32,128)
    const float* __restrict__ gamma,
    const float* __restrict__ beta,
    float* __restrict__ out)                 // (B, 64, N)
{
    __shared__ float tile[64 * 65];
    __shared__ float colsum[128];
    __shared__ float sc[64], bi[64];
    const int tid = threadIdx.x;

    if (tid < 128) {
        float v = 0.f;
        #pragma unroll
        for (int i = 0; i < 32; ++i) v += statsN[i * 128 + tid];
        colsum[tid] = v;
    }
    __syncthreads();
    if (tid < 64) {
        float mean = colsum[tid] * (1.0f / BNK_F);
        float var  = colsum[64 + tid] * (1.0f / BNK_F) - mean * mean;
        float s    = gamma[tid] * rsqrtf(var + 1e-5f);
        sc[tid] = s;
        bi[tid] = beta[tid] - mean * s;
    }
    __syncthreads();

    const int b  = blockIdx.x >> 8;
    const int n0 = (blockIdx.x & 255) << 6;
    const size_t bn0 = (size_t)b * NDIM + n0;
    const int c4 = tid & 15;

    for (int r = tid >> 4; r < 64; r += 16) {
        uint2 u = *(const uint2*)&hselp[(bn0 + r) * 32 + c4 * 2];
        float v0 = fmaf(sc[4 * c4],     __uint_as_float(u.x << 16),         bi[4 * c4]);
        float v1 = fmaf(sc[4 * c4 + 1], __uint_as_float(u.x & 0xffff0000u), bi[4 * c4 + 1]);
        float v2 = fmaf(sc[4 * c4 + 2], __uint_as_float(u.y << 16),         bi[4 * c4 + 2]);
        float v3 = fmaf(sc[4 * c4 + 3], __uint_as_float(u.y & 0xffff0000u), bi[4 * c4 + 3]);
        v0 = (v0 >= 0.f) ? v0 : 0.2f * v0;
        v1 = (v1 >= 0.f) ? v1 : 0.2f * v1;
        v2 = (v2 >= 0.f) ? v2 : 0.2f * v2;
        v3 = (v3 >= 0.f) ? v3 : 0.2f * v3;
        tile[r * 65 + 4 * c4]     = v0;
        tile[r * 65 + 4 * c4 + 1] = v1;
        tile[r * 65 + 4 * c4 + 2] = v2;
        tile[r * 65 + 4 * c4 + 3] = v3;
    }
    __syncthreads();
    const int ln = tid & 15;
    for (int o = tid >> 4; o < 64; o += 16) {
        f32x4_t v;
        v[0] = tile[(ln * 4 + 0) * 65 + o];
        v[1] = tile[(ln * 4 + 1) * 65 + o];
        v[2] = tile[(ln * 4 + 2) * 65 + o];
        v[3] = tile[(ln * 4 + 3) * 65 + o];
        *(f32x4_t*)&out[((size_t)(b * 64 + o) << 14) + n0 + ln * 4] = v;
    }
}

extern "C" void kernel_launch(void* const* d_in, const int* in_sizes, int n_in,
                              void* d_out, int out_size, void* d_ws, size_t ws_size,
                              hipStream_t stream) {
    const float* x     = (const float*)d_in[0];
    const int*   ei    = (const int*)d_in[1];
    const float* W     = (const float*)d_in[2];
    const float* gamma = (const float*)d_in[3];
    const float* beta  = (const float*)d_in[4];
    float* out = (float*)d_out;

    char* ws = (char*)d_ws;
    unsigned* y1p    = (unsigned*)(ws);                       // 8 MiB (bf16 pairs)
    unsigned* y2p    = (unsigned*)(ws + 8388608);             // 8 MiB
    unsigned* hselp  = (unsigned*)(ws + 16777216);            // 8 MiB
    float*    statsN = (float*)(ws + 25165824);               // 16 KiB (32x128)

    gemm_mfma_kernel <<<dim3(1024), dim3(256), 0, stream>>>(x, W, y1p, y2p, statsN);
    gather_kernel    <<<dim3(2048), dim3(256), 0, stream>>>(y1p, y2p, ei, gamma, hselp, statsN);
    out_kernel       <<<dim3(1024), dim3(256), 0, stream>>>(hselp, statsN, gamma, beta, out);
}

// Round 8
// 101.879 us; speedup vs baseline: 4.5556x; 1.0229x over previous
//
#include <hip/hip_runtime.h>
#include <hip/hip_bf16.h>
#include <stdint.h>

// B=4, C=64, N=16384, K=16, CO=64 (fp32 I/O, int32 idx)
// R8 = R7 + k2 index-machinery swap:
//  - wave's 128 edge indices loaded via 2 coalesced vector loads at kernel top
//    (kills the per-rp s_load/lgkmcnt serial chain = the inter-burst bubble)
//  - per-gather index broadcast via ds_bpermute (DS pipe) instead of
//    v_cndmask from SGPRs (VALU) -> 1 less VALU/gather
//  - y1 dwords prefetched at top (consumed last)
//  Burst/consume structure and ALL math identical to R7 -> bit-identical out.
// Attribution (R6 probe): k1<=7.7us, k2~15.5us (latency-bound), k3<=3.9us
// (HBM floor); ~77us of bench dur is harness fixed cost.
#define NDIM 16384
#define KNB 16
#define BNK_F 1048576.0f

typedef __attribute__((ext_vector_type(8))) short bf16x8_t;
typedef __attribute__((ext_vector_type(4))) float f32x4_t;
typedef __attribute__((ext_vector_type(2))) float f32x2_t;

__device__ inline unsigned pack_bf16(float a, float b) {
    return (unsigned)__bfloat16_as_ushort(__float2bfloat16(a))
         | ((unsigned)__bfloat16_as_ushort(__float2bfloat16(b)) << 16);
}

// ---------------- Kernel 1: MFMA GEMM (R7-proven, unchanged) ----------------
__global__ __launch_bounds__(256) void gemm_mfma_kernel(
    const float* __restrict__ x,            // (B, 64, N)
    const float* __restrict__ W,            // (64, 128)
    unsigned* __restrict__ y1p,             // (B,N,32) bf16-pairs
    unsigned* __restrict__ y2p,             // (B,N,32) bf16-pairs
    float* __restrict__ statsN)             // (32,128) striped stats - zeroed here
{
    __shared__ alignas(16) short lds_a[128 * 72];  // row pad 72 -> 2-way-free b128
    __shared__ alignas(16) short lds_b[64 * 72];   // x tile, n-major

    const int tid = threadIdx.x;
    if (blockIdx.x == 0) {
        for (int i = tid; i < 4096; i += 256) statsN[i] = 0.0f;
    }
    const int b  = blockIdx.x >> 8;
    const int n0 = (blockIdx.x & 255) << 6;

    for (int idx = tid; idx < 1024; idx += 256) {
        const int r = idx >> 4, q = idx & 15;
        const f32x4_t wa = *(const f32x4_t*)&W[r * 128 + q * 4];
        const f32x4_t wb = *(const f32x4_t*)&W[r * 128 + 64 + q * 4];
        const f32x4_t wsum = wa + wb;                  // v_pk_add_f32
        uint2 pa = { pack_bf16(wsum[0], wsum[1]), pack_bf16(wsum[2], wsum[3]) };
        uint2 pb = { pack_bf16(wb[0], wb[1]),     pack_bf16(wb[2], wb[3]) };
        *(uint2*)&lds_a[r * 72 + q * 4]        = pa;
        *(uint2*)&lds_a[(64 + r) * 72 + q * 4] = pb;
    }
    {
        const float* xb = x + (size_t)b * 64 * NDIM + n0;
        const int n = tid & 63;
        unsigned* lb32 = (unsigned*)lds_b;
        for (int cp = tid >> 6; cp < 32; cp += 4) {
            int c = cp * 2;
            float x0 = xb[(size_t)c * NDIM + n];
            float x1 = xb[(size_t)(c + 1) * NDIM + n];
            lb32[n * 36 + cp] = pack_bf16(x0, x1);
        }
    }
    __syncthreads();

    const int lane = tid & 63;
    const int w    = tid >> 6;
    const int m    = lane & 15;
    const int q    = lane >> 4;
    const int n    = w * 16 + m;

    const bf16x8_t b0 = *(const bf16x8_t*)&lds_b[n * 72 + q * 8];
    const bf16x8_t b1 = *(const bf16x8_t*)&lds_b[n * 72 + q * 8 + 32];

    const size_t rowbase = ((size_t)(b * NDIM + n0 + n)) * 32;
    #pragma unroll
    for (int t = 0; t < 8; ++t) {
        const short* ap = &lds_a[(t * 16 + m) * 72 + q * 8];
        bf16x8_t a0 = *(const bf16x8_t*)ap;
        bf16x8_t a1 = *(const bf16x8_t*)(ap + 32);
        f32x4_t acc = {0.f, 0.f, 0.f, 0.f};
        acc = __builtin_amdgcn_mfma_f32_16x16x32_bf16(a0, b0, acc, 0, 0, 0);
        acc = __builtin_amdgcn_mfma_f32_16x16x32_bf16(a1, b1, acc, 0, 0, 0);
        unsigned* dst = (t < 4) ? y1p : y2p;
        uint2 pk = { pack_bf16(acc[0], acc[1]), pack_bf16(acc[2], acc[3]) };
        *(uint2*)&dst[rowbase + (t & 3) * 8 + q * 2] = pk;
    }
}

// ---------------- Kernel 2: gather, vector-idx + bpermute broadcast ----------------
// 2048 blocks x 256, XCD-pinned batches. 32 outstanding gathers/wave (R0 bursts).
__global__ __launch_bounds__(256, 4) void gather_kernel(
    const unsigned* __restrict__ y1p,        // (B,N,32) bf16-pairs
    const unsigned* __restrict__ y2p,
    const int* __restrict__ ei,              // (B, N, 16)
    const float* __restrict__ gamma,
    unsigned* __restrict__ hselp,            // (B,N,32) bf16-pairs
    float* __restrict__ statsN)              // (32,128)
{
    const int tid  = threadIdx.x;
    const int w    = __builtin_amdgcn_readfirstlane(tid >> 6);
    const int lane = tid & 63;
    const int half = lane >> 5;
    const int c2   = lane & 31;
    const int g    = blockIdx.x;
    const int xcd  = g & 7;
    const int b    = xcd >> 1;
    const int row0 = b * NDIM + (xcd & 1) * 8192 + (g >> 3) * 32 + w * 8;

    // 128 wave indices (rows row0..row0+7): 2 coalesced vector loads, issued first
    const int idx0 = ei[(size_t)row0 * KNB + lane];        // rows row0..row0+3
    const int idx1 = ei[(size_t)row0 * KNB + 64 + lane];   // rows row0+4..row0+7
    // y1 prefetch (consumed at the end of each p-phase)
    const unsigned y1A = y1p[(size_t)(row0 + 0 + half) * 32 + c2];
    const unsigned y1B = y1p[(size_t)(row0 + 2 + half) * 32 + c2];
    const unsigned y1C = y1p[(size_t)(row0 + 4 + half) * 32 + c2];
    const unsigned y1D = y1p[(size_t)(row0 + 6 + half) * 32 + c2];

    const unsigned sgn0 = (gamma[2 * c2]     >= 0.0f) ? 0x80000000u : 0u;
    const unsigned sgn1 = (gamma[2 * c2 + 1] >= 0.0f) ? 0x80000000u : 0u;
    const char* y2base = (const char*)y2p + (size_t)b * NDIM * 128;
    const unsigned coff = (unsigned)(c2 << 2);
    const int hb = half << 6;     // byte addr of this lane's source-lane base

    f32x2_t ssum = {0.f, 0.f};
    f32x2_t ssq  = {0.f, 0.f};

    #pragma unroll
    for (int t = 0; t < 2; ++t) {
        const int srci = t ? idx1 : idx0;
        const int ra = row0 + t * 4;         // pair0: rows ra, ra+1
        const int rb = ra + 2;               // pair1: rows rb, rb+1
        const unsigned y1u0 = t ? y1C : y1A;
        const unsigned y1u1 = t ? y1D : y1B;

        unsigned u0[KNB], u1[KNB];
        #pragma unroll
        for (int k = 0; k < KNB; ++k) {
            // row (ra+half)'s index k lives in lane half*16+k of srci
            int j = __builtin_amdgcn_ds_bpermute(hb + 4 * k, srci);
            u0[k] = *(const unsigned*)(y2base + ((((unsigned)j) << 7) + coff));
        }
        #pragma unroll
        for (int k = 0; k < KNB; ++k) {
            // row (rb+half)'s index k lives in lane 32+half*16+k
            int j = __builtin_amdgcn_ds_bpermute(128 + hb + 4 * k, srci);
            u1[k] = *(const unsigned*)(y2base + ((((unsigned)j) << 7) + coff));
        }

        #pragma unroll 2
        for (int p = 0; p < 2; ++p) {
            const unsigned* u = (p == 0) ? u0 : u1;
            const unsigned y1u = (p == 0) ? y1u0 : y1u1;
            const int rw = ((p == 0) ? ra : rb) + half;

            f32x2_t s2 = {0.f, 0.f};
            f32x2_t q2 = {0.f, 0.f};
            float M0 = -3.402823e38f, M1 = -3.402823e38f;
            #pragma unroll
            for (int k = 0; k < KNB; k += 2) {
                unsigned lo0 = u[k] << 16,     hi0 = u[k] & 0xffff0000u;
                unsigned lo1 = u[k + 1] << 16, hi1 = u[k + 1] & 0xffff0000u;
                f32x2_t v0 = { __uint_as_float(lo0), __uint_as_float(hi0) };
                f32x2_t v1 = { __uint_as_float(lo1), __uint_as_float(hi1) };
                s2 += v0;                                          // v_pk_add_f32
                q2 = __builtin_elementwise_fma(v0, v0, q2);        // v_pk_fma_f32
                s2 += v1;
                q2 = __builtin_elementwise_fma(v1, v1, q2);
                M0 = fmaxf(fmaxf(M0, __uint_as_float(lo0 ^ sgn0)),
                           __uint_as_float(lo1 ^ sgn0));           // v_max3_f32
                M1 = fmaxf(fmaxf(M1, __uint_as_float(hi0 ^ sgn1)),
                           __uint_as_float(hi1 ^ sgn1));
            }
            const f32x2_t y1v = { __uint_as_float(y1u << 16),
                                  __uint_as_float(y1u & 0xffff0000u) };
            const float h0 = y1v.x - __uint_as_float(__float_as_uint(M0) ^ sgn0);
            const float h1 = y1v.y - __uint_as_float(__float_as_uint(M1) ^ sgn1);
            hselp[(size_t)rw * 32 + c2] = pack_bf16(h0, h1);
            ssum += (f32x2_t){16.f, 16.f} * y1v - s2;
            ssq  += __builtin_elementwise_fma(
                        __builtin_elementwise_fma((f32x2_t){-2.f, -2.f}, s2,
                                                  (f32x2_t){16.f, 16.f} * y1v),
                        y1v, q2);
        }
    }

    __shared__ float rs[8][64];
    __shared__ float rq[8][64];
    rs[w * 2 + half][c2 * 2]     = ssum.x;
    rs[w * 2 + half][c2 * 2 + 1] = ssum.y;
    rq[w * 2 + half][c2 * 2]     = ssq.x;
    rq[w * 2 + half][c2 * 2 + 1] = ssq.y;
    __syncthreads();
    if (tid < 128) {
        const int c = tid & 63;
        float v = 0.f;
        if (tid < 64) { for (int r = 0; r < 8; ++r) v += rs[r][c]; }
        else          { for (int r = 0; r < 8; ++r) v += rq[r][c]; }
        atomicAdd(&statsN[(g & 31) * 128 + tid], v);   // striped: ~64 adds/line
    }
}

// ---------------- Kernel 3: reduce-in-prologue + affine + leaky + transpose ----------------
__global__ __launch_bounds__(256) void out_kernel(
    const unsigned* __restrict__ hselp,      // (B,N,32) bf16-pairs
    const float* __restrict__ statsN,        // (32,128)
    const float* __restrict__ gamma,
    const float* __restrict__ beta,
    float* __restrict__ out)                 // (B, 64, N)
{
    __shared__ float tile[64 * 65];
    __shared__ float colsum[128];
    __shared__ float sc[64], bi[64];
    const int tid = threadIdx.x;

    if (tid < 128) {
        float v = 0.f;
        #pragma unroll
        for (int i = 0; i < 32; ++i) v += statsN[i * 128 + tid];
        colsum[tid] = v;
    }
    __syncthreads();
    if (tid < 64) {
        float mean = colsum[tid] * (1.0f / BNK_F);
        float var  = colsum[64 + tid] * (1.0f / BNK_F) - mean * mean;
        float s    = gamma[tid] * rsqrtf(var + 1e-5f);
        sc[tid] = s;
        bi[tid] = beta[tid] - mean * s;
    }
    __syncthreads();

    const int b  = blockIdx.x >> 8;
    const int n0 = (blockIdx.x & 255) << 6;
    const size_t bn0 = (size_t)b * NDIM + n0;
    const int c4 = tid & 15;

    for (int r = tid >> 4; r < 64; r += 16) {
        uint2 u = *(const uint2*)&hselp[(bn0 + r) * 32 + c4 * 2];
        float v0 = fmaf(sc[4 * c4],     __uint_as_float(u.x << 16),         bi[4 * c4]);
        float v1 = fmaf(sc[4 * c4 + 1], __uint_as_float(u.x & 0xffff0000u), bi[4 * c4 + 1]);
        float v2 = fmaf(sc[4 * c4 + 2], __uint_as_float(u.y << 16),         bi[4 * c4 + 2]);
        float v3 = fmaf(sc[4 * c4 + 3], __uint_as_float(u.y & 0xffff0000u), bi[4 * c4 + 3]);
        v0 = (v0 >= 0.f) ? v0 : 0.2f * v0;
        v1 = (v1 >= 0.f) ? v1 : 0.2f * v1;
        v2 = (v2 >= 0.f) ? v2 : 0.2f * v2;
        v3 = (v3 >= 0.f) ? v3 : 0.2f * v3;
        tile[r * 65 + 4 * c4]     = v0;
        tile[r * 65 + 4 * c4 + 1] = v1;
        tile[r * 65 + 4 * c4 + 2] = v2;
        tile[r * 65 + 4 * c4 + 3] = v3;
    }
    __syncthreads();
    const int ln = tid & 15;
    for (int o = tid >> 4; o < 64; o += 16) {
        f32x4_t v;
        v[0] = tile[(ln * 4 + 0) * 65 + o];
        v[1] = tile[(ln * 4 + 1) * 65 + o];
        v[2] = tile[(ln * 4 + 2) * 65 + o];
        v[3] = tile[(ln * 4 + 3) * 65 + o];
        *(f32x4_t*)&out[((size_t)(b * 64 + o) << 14) + n0 + ln * 4] = v;
    }
}

extern "C" void kernel_launch(void* const* d_in, const int* in_sizes, int n_in,
                              void* d_out, int out_size, void* d_ws, size_t ws_size,
                              hipStream_t stream) {
    const float* x     = (const float*)d_in[0];
    const int*   ei    = (const int*)d_in[1];
    const float* W     = (const float*)d_in[2];
    const float* gamma = (const float*)d_in[3];
    const float* beta  = (const float*)d_in[4];
    float* out = (float*)d_out;

    char* ws = (char*)d_ws;
    unsigned* y1p    = (unsigned*)(ws);                       // 8 MiB (bf16 pairs)
    unsigned* y2p    = (unsigned*)(ws + 8388608);             // 8 MiB
    unsigned* hselp  = (unsigned*)(ws + 16777216);            // 8 MiB
    float*    statsN = (float*)(ws + 25165824);               // 16 KiB (32x128)

    gemm_mfma_kernel <<<dim3(1024), dim3(256), 0, stream>>>(x, W, y1p, y2p, statsN);
    gather_kernel    <<<dim3(2048), dim3(256), 0, stream>>>(y1p, y2p, ei, gamma, hselp, statsN);
    out_kernel       <<<dim3(1024), dim3(256), 0, stream>>>(hselp, statsN, gamma, beta, out);
}